// Round 5
// baseline (650.175 us; speedup 1.0000x reference)
//
#include <hip/hip_runtime.h>
#include <math.h>

#define PI_F 3.14159265358979323846f

typedef _Float16 h8 __attribute__((ext_vector_type(8)));
typedef float f4 __attribute__((ext_vector_type(4)));

__device__ __forceinline__ float sigm_(float x){ return 1.0f/(1.0f+__expf(-x)); }
__device__ __forceinline__ float silu_(float x){ return x*sigm_(x); }
__device__ __forceinline__ h8 ldh8(const _Float16* p){
    return __builtin_bit_cast(h8, *(const float4*)(p));
}

// B layout (fp16, in d_ws):
//   B1T: per layer [n<112][k<192]  (n<50: Ws col, 50..99: Wg col, 100+: 0)
//   B2T: per layer [n<64][k<192]   (n<50: Wv col, else 0)
//   k segments: [0,50): W_hi(c=k) | [64,114): W_hi(c=k-64) | [128,178): W_lo(c=k-128)
#define B1_PER_L 21504
#define B2_PER_L 12288
#define B1_TOT   129024
#define B_TOT    202752

// ---------------------------------------------------------------------------
// K1 (merged): block 0 = pre[] + output boundary zeros; blocks [1..nTb] =
// spine table (4 entries/block, 1/wave); blocks (nTb..] = fill_B.
// ---------------------------------------------------------------------------
__global__ void precompute_all(const float* __restrict__ W_embed,
                               const float* __restrict__ Wr1,
                               const float* __restrict__ br1,
                               const float* __restrict__ Wr2,
                               const float* __restrict__ Ws,
                               const float* __restrict__ Wg,
                               const float* __restrict__ Wv,
                               float* __restrict__ pre,
                               float* __restrict__ T,
                               int tabN,
                               _Float16* __restrict__ B,
                               float* __restrict__ out,
                               int nTb)
{
    const int bid = blockIdx.x;
    const int tid = threadIdx.x;
    const float wdt = 0.06f / 9.0f;

    if (bid == 0) {
        for (int i = tid; i < 384; i += 256) {
            int b = i / 6, r = i - b * 6;
            int t = (r < 3) ? 0 : 513;
            out[((size_t)(b * 514 + t)) * 3 + (r % 3)] = 0.0f;
        }
        __shared__ float s1[50];
        __shared__ float hid[64];
        if (tid < 50) s1[tid] = W_embed[tid] + W_embed[50 + tid];
        __syncthreads();

        const float rbar = 0.05f;
        const float fcb = 0.5f * (__cosf(PI_F * (rbar / 0.06f)) + 1.0f);
        float emb[12];
#pragma unroll
        for (int i = 0; i < 10; ++i) {
            float d = (rbar - (float)i * wdt) / wdt;
            emb[i] = __expf(-d * d) * fcb;
        }
        emb[10] = 0.0f; emb[11] = 1.0f;

        for (int l = 0; l < 6; ++l) {
            if (tid < 50) pre[l * 50 + tid] = s1[tid];
            if (tid < 64) {
                float a = br1[l * 64 + tid];
#pragma unroll
                for (int i = 0; i < 12; ++i) a += emb[i] * Wr1[l * 768 + i * 64 + tid];
                hid[tid] = silu_(a);
            }
            __syncthreads();
            for (int m = tid; m < 250; m += 256) {
                float acc = 0.0f;
                for (int j = 0; j < 64; ++j) acc += hid[j] * Wr2[l * 16000 + j * 250 + m];
                pre[300 + l * 250 + m] = acc * fcb;
            }
            float sacc = 0.0f;
            if (tid < 50) {
                for (int c = 0; c < 50; ++c) sacc += s1[c] * Ws[l * 2500 + c * 50 + tid];
            }
            __syncthreads();
            if (tid < 50) s1[tid] = silu_(sacc);
            __syncthreads();
        }
    } else if (bid <= nTb) {
        const int e = (bid - 1) * 4 + (tid >> 6);
        const int lane = tid & 63;
        const int total = 6 * (tabN + 1);
        if (e >= total) return;
        const int l = e / (tabN + 1);
        const int i = e - l * (tabN + 1);

        float r = (float)i * (0.06f / (float)tabN);
        float t = fminf(r * (1.0f / 0.06f), 1.0f);
        float fc = 0.5f * (__cosf(PI_F * t) + 1.0f);
        float emb[10];
#pragma unroll
        for (int k = 0; k < 10; ++k) {
            float d = (r - (float)k * wdt) / wdt;
            emb[k] = __expf(-d * d) * fc;
        }
        float a = br1[l * 64 + lane] + Wr1[l * 768 + 640 + lane];
#pragma unroll
        for (int k = 0; k < 10; ++k) a += emb[k] * Wr1[l * 768 + k * 64 + lane];
        float hv = silu_(a);

        float acc0 = 0.0f, acc1 = 0.0f;
        const float* wr2 = Wr2 + l * 16000;
        for (int j = 0; j < 64; ++j) {
            float hj = __shfl(hv, j);
            acc0 += hj * wr2[j * 250 + lane];
            acc1 += hj * wr2[j * 250 + 64 + lane];
        }
        float* tp = T + (size_t)e * 100;
        tp[lane] = acc0 * fc;
        if (lane < 36) tp[64 + lane] = acc1 * fc;
    } else {
        int idx = (bid - 1 - nTb) * 256 + tid;
        if (idx >= B_TOT) return;
        int l, n, k, which;
        size_t off;
        if (idx < B1_TOT) {
            l = idx / B1_PER_L; int r = idx - l * B1_PER_L;
            n = r / 192; k = r - n * 192; which = 0;
            off = (size_t)l * B1_PER_L + n * 192 + k;
        } else {
            int j = idx - B1_TOT;
            l = j / B2_PER_L; int r = j - l * B2_PER_L;
            n = r / 192; k = r - n * 192; which = 1;
            off = B1_TOT + (size_t)l * B2_PER_L + n * 192 + k;
        }
        int seg = -1, c = 0;
        if (k < 50)                  { seg = 0; c = k; }
        else if (k >= 64 && k < 114) { seg = 1; c = k - 64; }
        else if (k >= 128 && k < 178){ seg = 2; c = k - 128; }
        _Float16 val = (_Float16)0.0f;
        if (seg >= 0) {
            float w = 0.0f;
            if (which == 0) {
                if (n < 50)       w = Ws[l * 2500 + c * 50 + n];
                else if (n < 100) w = Wg[l * 2500 + c * 50 + (n - 50)];
            } else {
                if (n < 50)       w = Wv[l * 2500 + c * 50 + n];
            }
            _Float16 hi = (_Float16)w;
            val = (seg < 2) ? hi : (_Float16)(w - (float)hi);
        }
        B[off] = val;
    }
}

// ---------------------------------------------------------------------------
// K2: fused forward. Block = 8 windows (2/wave). m-loop-outer MFMA phase:
// each wave loads A-frags ONCE per m-tile job and loops n over B (global/L2).
// Jobs: wave w: H m-tile (w>>1) x n-tiles (even: 0-3, odd: 4-6);
//              Q m-tile w x n-tiles 0-3; odd waves: Q m-tile 4 x 2 n-tiles.
// ---------------------------------------------------------------------------
__global__ __launch_bounds__(256, 4)
void fused_main(const float* __restrict__ y,
                const float* __restrict__ W_embed,
                const float* __restrict__ W_out,
                const float* __restrict__ pre,
                const float* __restrict__ T,
                int tabN,
                const _Float16* __restrict__ Bws,
                float* __restrict__ out)
{
    __shared__ __align__(16) char LB[112 * 152 * 2];   // 34048 B
    _Float16* A   = (_Float16*)LB;
    float* outHT  = (float*)LB;          // [32][100]
    float* outQT  = (float*)LB + 3200;   // [80][50]

    const int tid  = threadIdx.x;
    const int wave = tid >> 6;
    const int lane = tid & 63;
    const int kl   = (lane < 50) ? lane : 49;
    const int fm   = lane & 15;
    const int fq   = lane >> 4;

    const _Float16* B1 = Bws;
    const _Float16* B2 = Bws + B1_TOT;

    // ---- per-window geometry ----
    float offx[2], offy[2], u3x_[2], u3y_[2], uspx_[2], uspy_[2], fr_[2];
    int   ti_[2], inr_[2];
#pragma unroll
    for (int w = 0; w < 2; ++w) {
        int wid = blockIdx.x * 8 + wave * 2 + w;
        int b = wid >> 9, tw = wid & 511;
        const float* yb = y + ((size_t)(b * 514 + tw)) * 6;
        float c0x = yb[0], c0y = yb[1];
        float c1x = yb[6], c1y = yb[7], a1 = yb[8];
        float sn, cs; __sincosf(a1, &sn, &cs);
        offx[w] = -0.05f * sn; offy[w] = 0.05f * cs;
        float svx = c0x - c1x, svy = c0y - c1y;
        float r_sp = sqrtf(svx * svx + svy * svy);
        float inv_sp = 1.0f / (r_sp + 1e-12f);
        uspx_[w] = svx * inv_sp; uspy_[w] = svy * inv_sp;
        float rb2 = sqrtf(offx[w] * offx[w] + offy[w] * offy[w]);
        float invb = 1.0f / (rb2 + 1e-12f);
        u3x_[w] = -offx[w] * invb; u3y_[w] = -offy[w] * invb;
        float tp = r_sp * ((float)tabN / 0.06f);
        inr_[w] = tp < (float)tabN;
        int ti = (int)tp;
        if (ti > tabN - 1) ti = tabN - 1;
        if (ti < 0) ti = 0;
        ti_[w] = ti; fr_[w] = tp - (float)ti;
    }

    // ---- initial states ----
    float s3[2], s4[2], s5[2];
    float v3x[2], v3y[2], v3z[2], v4x[2], v4y[2], v4z[2], v5x[2], v5y[2], v5z[2];
    {
        float i35 = W_embed[kl] + W_embed[100 + kl];
        float i4  = W_embed[kl] + W_embed[50 + kl];
#pragma unroll
        for (int w = 0; w < 2; ++w) {
            s3[w] = i35; s5[w] = i35; s4[w] = i4;
            v3x[w] = v3y[w] = v3z[w] = 0.0f;
            v4x[w] = v4y[w] = v4z[w] = 0.0f;
            v5x[w] = v5y[w] = v5z[w] = 0.0f;
        }
    }

    const int  mh  = wave >> 1;
    const bool odd = wave & 1;

    for (int l = 0; l < 6; ++l) {
        __syncthreads();   // overlay region free

        float s1l = pre[l * 50 + kl];
        const float* wbp = pre + 300 + l * 250;
        float wb0 = wbp[kl], wb1 = wbp[50 + kl], wb2 = wbp[100 + kl],
              wb3 = wbp[150 + kl], wb4 = wbp[200 + kl];

        const float THIRD = 1.0f / 3.0f;
#pragma unroll
        for (int w = 0; w < 2; ++w) {
            const float* tb = T + ((size_t)(l * (tabN + 1) + ti_[w])) * 100;
            float t00 = tb[kl], t01 = tb[50 + kl], t10 = tb[100 + kl], t11 = tb[150 + kl];
            float wsp0 = inr_[w] ? (t00 + fr_[w] * (t10 - t00)) : 0.0f;
            float wsp1 = inr_[w] ? (t01 + fr_[w] * (t11 - t01)) : 0.0f;

            float u3x = u3x_[w], u3y = u3y_[w];
            float dot3 = v4x[w] * u3x + v4y[w] * u3y;
            float ms3 = wb0 * s4[w] + wb2 * dot3;
            float ms5 = wb0 * s4[w] - wb2 * dot3;
            float ms4 = wsp0 * s1l;
            float bAx = wb1 * s4[w] * u3x - wb3 * v4z[w] * u3y;
            float bAy = wb1 * s4[w] * u3y + wb3 * v4z[w] * u3x;
            float bBx = wb4 * (dot3 * u3x - v4x[w] * THIRD);
            float bBy = wb4 * (dot3 * u3y - v4y[w] * THIRD);
            float crz = wb3 * (v4x[w] * u3y - v4y[w] * u3x);
            float mzc = -wb4 * v4z[w] * THIRD;

            float vals[12];
            vals[0] = s3[w] + ms3;
            vals[1] = s4[w] + ms4;
            vals[2] = s5[w] + ms5;
            vals[3] = v3x[w] + bAx + bBx;
            vals[4] = v3y[w] + bAy + bBy;
            vals[5] = v3z[w] + crz + mzc;
            vals[6] = v4x[w] + wsp1 * s1l * uspx_[w];
            vals[7] = v4y[w] + wsp1 * s1l * uspy_[w];
            vals[8] = v4z[w];
            vals[9]  = v5x[w] - bAx + bBx;
            vals[10] = v5y[w] - bAy + bBy;
            vals[11] = v5z[w] - crz + mzc;

            int wv = wave * 2 + w;
#pragma unroll
            for (int q = 0; q < 12; ++q) {
                int row = (q < 3) ? (wv * 3 + q) : (32 + wv * 9 + (q - 3));
                float x = (lane < 50) ? vals[q] : 0.0f;
                _Float16 hi = (_Float16)x;
                _Float16 lo = (_Float16)(x - (float)hi);
                A[row * 152 + lane]      = hi;
                A[row * 152 + 64 + lane] = lo;
            }
        }
        {
            int pr  = tid >> 4;
            int row = (pr < 8) ? (24 + pr) : (96 + pr);
            f4 z = {0.0f, 0.0f, 0.0f, 0.0f};
            *(f4*)(A + row * 152 + (tid & 15) * 8) = z;
        }
        __syncthreads();   // A complete

        // ---- MFMA phase (m-outer, A loaded once per job) ----
        f4 hacc[4], qacc[4], q4acc[2];
        const _Float16* B1l = B1 + (size_t)l * B1_PER_L;
        const _Float16* B2l = B2 + (size_t)l * B2_PER_L;

#define NTILE(ACC, BMAT) { \
            h8 b0 = ldh8(bp), b1 = ldh8(bp + 32), b2 = ldh8(bp + 64), \
               b3 = ldh8(bp + 96), b4 = ldh8(bp + 128), b5 = ldh8(bp + 160); \
            f4 acc = {0.0f, 0.0f, 0.0f, 0.0f}; \
            acc = __builtin_amdgcn_mfma_f32_16x16x32_f16(a0, b0, acc, 0, 0, 0); \
            acc = __builtin_amdgcn_mfma_f32_16x16x32_f16(a1, b1, acc, 0, 0, 0); \
            acc = __builtin_amdgcn_mfma_f32_16x16x32_f16(a2, b2, acc, 0, 0, 0); \
            acc = __builtin_amdgcn_mfma_f32_16x16x32_f16(a3, b3, acc, 0, 0, 0); \
            acc = __builtin_amdgcn_mfma_f32_16x16x32_f16(a0, b4, acc, 0, 0, 0); \
            acc = __builtin_amdgcn_mfma_f32_16x16x32_f16(a1, b5, acc, 0, 0, 0); \
            ACC = acc; }

        // Job 1: H GEMM, m-tile mh
        {
            const _Float16* ap = A + (mh * 16 + fm) * 152 + fq * 8;
            h8 a0 = ldh8(ap), a1 = ldh8(ap + 32), a2 = ldh8(ap + 64), a3 = ldh8(ap + 96);
            if (!odd) {
                { const _Float16* bp = B1l + (0 * 16 + fm) * 192 + fq * 8; NTILE(hacc[0], B1l) }
                { const _Float16* bp = B1l + (1 * 16 + fm) * 192 + fq * 8; NTILE(hacc[1], B1l) }
                { const _Float16* bp = B1l + (2 * 16 + fm) * 192 + fq * 8; NTILE(hacc[2], B1l) }
                { const _Float16* bp = B1l + (3 * 16 + fm) * 192 + fq * 8; NTILE(hacc[3], B1l) }
            } else {
                { const _Float16* bp = B1l + (4 * 16 + fm) * 192 + fq * 8; NTILE(hacc[0], B1l) }
                { const _Float16* bp = B1l + (5 * 16 + fm) * 192 + fq * 8; NTILE(hacc[1], B1l) }
                { const _Float16* bp = B1l + (6 * 16 + fm) * 192 + fq * 8; NTILE(hacc[2], B1l) }
            }
        }
        // Job 2: Q GEMM, m-tile = wave
        {
            const _Float16* ap = A + (32 + wave * 16 + fm) * 152 + fq * 8;
            h8 a0 = ldh8(ap), a1 = ldh8(ap + 32), a2 = ldh8(ap + 64), a3 = ldh8(ap + 96);
            { const _Float16* bp = B2l + (0 * 16 + fm) * 192 + fq * 8; NTILE(qacc[0], B2l) }
            { const _Float16* bp = B2l + (1 * 16 + fm) * 192 + fq * 8; NTILE(qacc[1], B2l) }
            { const _Float16* bp = B2l + (2 * 16 + fm) * 192 + fq * 8; NTILE(qacc[2], B2l) }
            { const _Float16* bp = B2l + (3 * 16 + fm) * 192 + fq * 8; NTILE(qacc[3], B2l) }
        }
        // Job 3 (odd waves): Q GEMM, m-tile 4, two n-tiles
        if (odd) {
            const _Float16* ap = A + (96 + fm) * 152 + fq * 8;
            h8 a0 = ldh8(ap), a1 = ldh8(ap + 32), a2 = ldh8(ap + 64), a3 = ldh8(ap + 96);
            int nb = (wave == 1) ? 0 : 2;
            { const _Float16* bp = B2l + ((nb    ) * 16 + fm) * 192 + fq * 8; NTILE(q4acc[0], B2l) }
            { const _Float16* bp = B2l + ((nb + 1) * 16 + fm) * 192 + fq * 8; NTILE(q4acc[1], B2l) }
        }
#undef NTILE
        __syncthreads();   // all A-reads done -> overlay safe

        // ---- C writes, transposed (conflict-free) ----
        {
#define HWR(slot, nt) { int n = (nt) * 16 + fm; if (n < 100) { \
            _Pragma("unroll") \
            for (int i = 0; i < 4; ++i) \
                outHT[(mh * 16 + fq * 4 + i) * 100 + n] = hacc[slot][i]; } }
            if (!odd) { HWR(0,0) HWR(1,1) HWR(2,2) HWR(3,3) }
            else      { HWR(0,4) HWR(1,5) HWR(2,6) }
#undef HWR
            if (fm < 50) { } // (guard folded below)
#pragma unroll
            for (int nt = 0; nt < 4; ++nt) {
                int n = nt * 16 + fm;
                if (n < 50) {
#pragma unroll
                    for (int i = 0; i < 4; ++i)
                        outQT[(wave * 16 + fq * 4 + i) * 50 + n] = qacc[nt][i];
                }
            }
            if (odd) {
                int nb = (wave == 1) ? 0 : 2;
#pragma unroll
                for (int k = 0; k < 2; ++k) {
                    int n = (nb + k) * 16 + fm;
                    if (n < 50) {
#pragma unroll
                        for (int i = 0; i < 4; ++i)
                            outQT[(64 + fq * 4 + i) * 50 + n] = q4acc[k][i];
                    }
                }
            }
        }
        __syncthreads();   // outputs ready

        // ---- readback + activations (stride-1: conflict-free) ----
#pragma unroll
        for (int w = 0; w < 2; ++w) {
            int wv = wave * 2 + w;
            int mb = wv * 3, qb = wv * 9;
            float as3 = outHT[(mb    ) * 100 + kl];
            float as4 = outHT[(mb + 1) * 100 + kl];
            float as5 = outHT[(mb + 2) * 100 + kl];
            float ag3 = outHT[(mb    ) * 100 + 50 + kl];
            float ag4 = outHT[(mb + 1) * 100 + 50 + kl];
            float ag5 = outHT[(mb + 2) * 100 + 50 + kl];
            float g3 = sigm_(ag3), g4 = sigm_(ag4), g5 = sigm_(ag5);
            s3[w] = silu_(as3); s4[w] = silu_(as4); s5[w] = silu_(as5);
            v3x[w] = outQT[(qb    ) * 50 + kl] * g3;
            v3y[w] = outQT[(qb + 1) * 50 + kl] * g3;
            v3z[w] = outQT[(qb + 2) * 50 + kl] * g3;
            v4x[w] = outQT[(qb + 3) * 50 + kl] * g4;
            v4y[w] = outQT[(qb + 4) * 50 + kl] * g4;
            v4z[w] = outQT[(qb + 5) * 50 + kl] * g4;
            v5x[w] = outQT[(qb + 6) * 50 + kl] * g5;
            v5y[w] = outQT[(qb + 7) * 50 + kl] * g5;
            v5z[w] = outQT[(qb + 8) * 50 + kl] * g5;
        }
    }

    // ---- output epilogue ----
    float wo = (lane < 50) ? W_out[lane] : 0.0f;
#pragma unroll
    for (int w = 0; w < 2; ++w) {
        float px  = (v3x[w] + v4x[w] + v5x[w]) * wo;
        float py  = (v3y[w] + v4y[w] + v5y[w]) * wo;
        float dxv = (v3x[w] - v5x[w]) * wo;
        float dyv = (v3y[w] - v5y[w]) * wo;
#pragma unroll
        for (int o = 32; o > 0; o >>= 1) {
            px  += __shfl_xor(px, o);
            py  += __shfl_xor(py, o);
            dxv += __shfl_xor(dxv, o);
            dyv += __shfl_xor(dyv, o);
        }
        if (lane == 0) {
            int wid = blockIdx.x * 8 + wave * 2 + w;
            int b = wid >> 9, tw = wid & 511;
            float* op = out + ((size_t)(b * 514 + (tw + 1))) * 3;
            op[0] = px;
            op[1] = py;
            op[2] = offx[w] * dyv - offy[w] * dxv;
        }
    }
}

// ---------------------------------------------------------------------------
extern "C" void kernel_launch(void* const* d_in, const int* in_sizes, int n_in,
                              void* d_out, int out_size, void* d_ws, size_t ws_size,
                              hipStream_t stream) {
    const float* y       = (const float*)d_in[0];
    const float* W_embed = (const float*)d_in[1];
    const float* Wr1     = (const float*)d_in[2];
    const float* br1     = (const float*)d_in[3];
    const float* Wr2     = (const float*)d_in[4];
    const float* Ws      = (const float*)d_in[5];
    const float* Wv      = (const float*)d_in[6];
    const float* Wg      = (const float*)d_in[7];
    const float* W_out   = (const float*)d_in[8];
    float* out = (float*)d_out;

    _Float16* Bws = (_Float16*)d_ws;                         // 405504 B
    float* pre = (float*)((char*)d_ws + B_TOT * 2);          // 1800 floats
    float* T   = pre + 1800;

    int tabN = 2048;
    while (tabN > 64 &&
           (size_t)B_TOT * 2 + (size_t)(1800 + 6 * (tabN + 1) * 100) * sizeof(float) > ws_size)
        tabN >>= 1;

    int nTb = (6 * (tabN + 1) + 3) / 4;
    int nFb = (B_TOT + 255) / 256;
    precompute_all<<<1 + nTb + nFb, 256, 0, stream>>>(
        W_embed, Wr1, br1, Wr2, Ws, Wg, Wv, pre, T, tabN, Bws, out, nTb);
    fused_main<<<4096, 256, 0, stream>>>(y, W_embed, W_out, pre, T, tabN, Bws, out);
}

// Round 7
// 333.156 us; speedup vs baseline: 1.9516x; 1.9516x over previous
//
#include <hip/hip_runtime.h>
#include <math.h>

#define PI_F 3.14159265358979323846f

typedef _Float16 h8 __attribute__((ext_vector_type(8)));
typedef float f4 __attribute__((ext_vector_type(4)));

__device__ __forceinline__ float sigm_(float x){ return 1.0f/(1.0f+__expf(-x)); }
__device__ __forceinline__ float silu_(float x){ return x*sigm_(x); }
__device__ __forceinline__ h8 ldh8(const _Float16* p){
    return __builtin_bit_cast(h8, *(const float4*)(p));
}

struct B5 { h8 b0, b1, b2, b3, b4; };
__device__ __forceinline__ B5 ldB5(const _Float16* p){
    B5 r; r.b0 = ldh8(p); r.b1 = ldh8(p + 32); r.b2 = ldh8(p + 64);
    r.b3 = ldh8(p + 96); r.b4 = ldh8(p + 128); return r;
}
__device__ __forceinline__ f4 tile5(const B5& a, const B5& b){
    f4 c = {0.f,0.f,0.f,0.f};
    c = __builtin_amdgcn_mfma_f32_16x16x32_f16(a.b0, b.b0, c, 0,0,0);
    c = __builtin_amdgcn_mfma_f32_16x16x32_f16(a.b1, b.b1, c, 0,0,0);
    c = __builtin_amdgcn_mfma_f32_16x16x32_f16(a.b2, b.b2, c, 0,0,0);
    c = __builtin_amdgcn_mfma_f32_16x16x32_f16(a.b3, b.b3, c, 0,0,0);
    c = __builtin_amdgcn_mfma_f32_16x16x32_f16(a.b4, b.b4, c, 0,0,0);
    return c;
}

// B layout (fp16, d_ws): per layer, rows [n][k<160]:
//   k=2c,2c+1 -> Whi(c) (c<50) ; k=100+c -> Wlo(c) (c<50) ; k in [150,160) -> 0
//   B1: n<50 Ws col, 50..99 Wg col, 100..111 zero.  B2: n<50 Wv col, 50..63 zero.
#define B1_PER_L 17920      // 112*160
#define B2_PER_L 10240      // 64*160
#define B1_TOT   107520
#define B_TOT    168960

// ---------------------------------------------------------------------------
// K1 (merged): block 0 = pre[] + output boundary zeros; blocks [1..nTb] =
// spine table; blocks (nTb..] = fill_B.
// ---------------------------------------------------------------------------
__global__ void precompute_all(const float* __restrict__ W_embed,
                               const float* __restrict__ Wr1,
                               const float* __restrict__ br1,
                               const float* __restrict__ Wr2,
                               const float* __restrict__ Ws,
                               const float* __restrict__ Wg,
                               const float* __restrict__ Wv,
                               float* __restrict__ pre,
                               float* __restrict__ T,
                               int tabN,
                               _Float16* __restrict__ B,
                               float* __restrict__ out,
                               int nTb)
{
    const int bid = blockIdx.x;
    const int tid = threadIdx.x;
    const float wdt = 0.06f / 9.0f;

    if (bid == 0) {
        for (int i = tid; i < 384; i += 256) {
            int b = i / 6, r = i - b * 6;
            int t = (r < 3) ? 0 : 513;
            out[((size_t)(b * 514 + t)) * 3 + (r % 3)] = 0.0f;
        }
        __shared__ float s1[50];
        __shared__ float hid[64];
        if (tid < 50) s1[tid] = W_embed[tid] + W_embed[50 + tid];
        __syncthreads();

        const float rbar = 0.05f;
        const float fcb = 0.5f * (__cosf(PI_F * (rbar / 0.06f)) + 1.0f);
        float emb[12];
#pragma unroll
        for (int i = 0; i < 10; ++i) {
            float d = (rbar - (float)i * wdt) / wdt;
            emb[i] = __expf(-d * d) * fcb;
        }
        emb[10] = 0.0f; emb[11] = 1.0f;

        for (int l = 0; l < 6; ++l) {
            if (tid < 50) pre[l * 50 + tid] = s1[tid];
            if (tid < 64) {
                float a = br1[l * 64 + tid];
#pragma unroll
                for (int i = 0; i < 12; ++i) a += emb[i] * Wr1[l * 768 + i * 64 + tid];
                hid[tid] = silu_(a);
            }
            __syncthreads();
            for (int m = tid; m < 250; m += 256) {
                float acc = 0.0f;
                for (int j = 0; j < 64; ++j) acc += hid[j] * Wr2[l * 16000 + j * 250 + m];
                pre[300 + l * 250 + m] = acc * fcb;
            }
            float sacc = 0.0f;
            if (tid < 50) {
                for (int c = 0; c < 50; ++c) sacc += s1[c] * Ws[l * 2500 + c * 50 + tid];
            }
            __syncthreads();
            if (tid < 50) s1[tid] = silu_(sacc);
            __syncthreads();
        }
    } else if (bid <= nTb) {
        const int e = (bid - 1) * 4 + (tid >> 6);
        const int lane = tid & 63;
        const int total = 6 * (tabN + 1);
        if (e >= total) return;
        const int l = e / (tabN + 1);
        const int i = e - l * (tabN + 1);

        float r = (float)i * (0.06f / (float)tabN);
        float t = fminf(r * (1.0f / 0.06f), 1.0f);
        float fc = 0.5f * (__cosf(PI_F * t) + 1.0f);
        float emb[10];
#pragma unroll
        for (int k = 0; k < 10; ++k) {
            float d = (r - (float)k * wdt) / wdt;
            emb[k] = __expf(-d * d) * fc;
        }
        float a = br1[l * 64 + lane] + Wr1[l * 768 + 640 + lane];
#pragma unroll
        for (int k = 0; k < 10; ++k) a += emb[k] * Wr1[l * 768 + k * 64 + lane];
        float hv = silu_(a);

        float acc0 = 0.0f, acc1 = 0.0f;
        const float* wr2 = Wr2 + l * 16000;
        for (int j = 0; j < 64; ++j) {
            float hj = __shfl(hv, j);
            acc0 += hj * wr2[j * 250 + lane];
            acc1 += hj * wr2[j * 250 + 64 + lane];
        }
        float* tp = T + (size_t)e * 100;
        tp[lane] = acc0 * fc;
        if (lane < 36) tp[64 + lane] = acc1 * fc;
    } else {
        int idx = (bid - 1 - nTb) * 256 + tid;
        if (idx >= B_TOT) return;
        int l, n, k; bool isB1;
        if (idx < B1_TOT) {
            isB1 = true;
            l = idx / B1_PER_L; int r = idx - l * B1_PER_L;
            n = r / 160; k = r - n * 160;
        } else {
            isB1 = false;
            int j = idx - B1_TOT;
            l = j / B2_PER_L; int r = j - l * B2_PER_L;
            n = r / 160; k = r - n * 160;
        }
        int c = (k < 100) ? (k >> 1) : (k - 100);
        float w = 0.0f;
        if (k < 150) {
            if (isB1) {
                if (n < 50)       w = Ws[l * 2500 + c * 50 + n];
                else if (n < 100) w = Wg[l * 2500 + c * 50 + (n - 50)];
            } else {
                if (n < 50)       w = Wv[l * 2500 + c * 50 + n];
            }
        }
        _Float16 hi = (_Float16)w;
        B[idx] = (k < 100) ? hi : (_Float16)(w - (float)hi);
    }
}

// ---------------------------------------------------------------------------
// K2: fused forward. Block = 4 windows (1 per wave), 8192 blocks.
// A: 64 rows x 168 halves (H rows 0..11 + pad; Q rows 16..51 + pad).
// Overlay after MFMA: outHT[16][100] (words 0..1599), outQT[48][50] (1600..4000).
// Per layer: prefetch B (global->regs) -> messages -> A-write (incl. per-row
// k-tail zeroing by lanes 50..54 — MUST be per-layer: the C overlay clobbers
// the tails; stale tails are 0xNaN fp16 and 0*NaN = NaN in MFMA) ->
// MFMA (A LDS, B regs) -> C-write transposed -> readback.
// ---------------------------------------------------------------------------
__global__ __launch_bounds__(256, 4)
void fused_main(const float* __restrict__ y,
                const float* __restrict__ W_embed,
                const float* __restrict__ W_out,
                const float* __restrict__ pre,
                const float* __restrict__ T,
                int tabN,
                const _Float16* __restrict__ Bws,
                float* __restrict__ out)
{
    __shared__ __align__(16) char LB[64 * 168 * 2];   // 21504 B
    _Float16* A   = (_Float16*)LB;
    unsigned* A32 = (unsigned*)LB;
    float* outHT  = (float*)LB;           // [16][100]
    float* outQT  = (float*)LB + 1600;    // [48][50]

    const int tid  = threadIdx.x;
    const int wave = tid >> 6;
    const int lane = tid & 63;
    const int kl   = (lane < 50) ? lane : 49;
    const int fm   = lane & 15;
    const int fq   = lane >> 4;

    // ---- geometry (one window per wave) ----
    const int wid = blockIdx.x * 4 + wave;
    const int b   = wid >> 9;
    const int tw  = wid & 511;
    float offx, offy, u3x, u3y, uspx, uspy, fr;
    int ti; bool inr;
    {
        const float* yb = y + ((size_t)(b * 514 + tw)) * 6;
        float c0x = yb[0], c0y = yb[1];
        float c1x = yb[6], c1y = yb[7], a1 = yb[8];
        float sn, cs; __sincosf(a1, &sn, &cs);
        offx = -0.05f * sn; offy = 0.05f * cs;
        float svx = c0x - c1x, svy = c0y - c1y;
        float r_sp = sqrtf(svx * svx + svy * svy);
        float inv_sp = 1.0f / (r_sp + 1e-12f);
        uspx = svx * inv_sp; uspy = svy * inv_sp;
        float rb2 = sqrtf(offx * offx + offy * offy);
        float invb = 1.0f / (rb2 + 1e-12f);
        u3x = -offx * invb; u3y = -offy * invb;
        float tp = r_sp * ((float)tabN / 0.06f);
        inr = tp < (float)tabN;
        int t0 = (int)tp;
        if (t0 > tabN - 1) t0 = tabN - 1;
        if (t0 < 0) t0 = 0;
        ti = t0; fr = tp - (float)t0;
    }

    // ---- initial state ----
    float s3, s4, s5, v3x=0, v3y=0, v3z=0, v4x=0, v4y=0, v4z=0, v5x=0, v5y=0, v5z=0;
    {
        float i35 = W_embed[kl] + W_embed[100 + kl];
        float i4  = W_embed[kl] + W_embed[50 + kl];
        s3 = i35; s5 = i35; s4 = i4;
    }

    for (int l = 0; l < 6; ++l) {
        // ---- B prefetch (global->regs), issued before VALU phase ----
        const _Float16* B1l = Bws + (size_t)l * B1_PER_L;
        const _Float16* B2l = Bws + B1_TOT + (size_t)l * B2_PER_L;
        const int fo = fm * 160 + fq * 8;
        const _Float16 *p0, *p1;
        if      (wave == 0) { p0 = B1l;            p1 = B1l + 2560; }
        else if (wave == 1) { p0 = B1l + 4 * 2560; p1 = B1l + 5 * 2560; }
        else if (wave == 2) { p0 = B2l;            p1 = B2l + 2560; }
        else                { p0 = B2l + 2 * 2560; p1 = B2l + 3 * 2560; }
        B5 bA = ldB5(p0 + fo);
        B5 bB = ldB5(p1 + fo);

        // ---- per-layer channel tables ----
        float s1l = pre[l * 50 + kl];
        const float* wbp = pre + 300 + l * 250;
        float wb0 = wbp[kl], wb1 = wbp[50 + kl], wb2 = wbp[100 + kl],
              wb3 = wbp[150 + kl], wb4 = wbp[200 + kl];
        const float* tb = T + ((size_t)(l * (tabN + 1) + ti)) * 100;
        float t00 = tb[kl], t01 = tb[50 + kl], t10 = tb[100 + kl], t11 = tb[150 + kl];
        float wsp0 = inr ? (t00 + fr * (t10 - t00)) : 0.0f;
        float wsp1 = inr ? (t01 + fr * (t11 - t01)) : 0.0f;

        // ---- messages ----
        const float THIRD = 1.0f / 3.0f;
        float dot3 = v4x * u3x + v4y * u3y;
        float ms3 = wb0 * s4 + wb2 * dot3;
        float ms5 = wb0 * s4 - wb2 * dot3;
        float ms4 = wsp0 * s1l;
        float bAx = wb1 * s4 * u3x - wb3 * v4z * u3y;
        float bAy = wb1 * s4 * u3y + wb3 * v4z * u3x;
        float bBx = wb4 * (dot3 * u3x - v4x * THIRD);
        float bBy = wb4 * (dot3 * u3y - v4y * THIRD);
        float crz = wb3 * (v4x * u3y - v4y * u3x);
        float mzc = -wb4 * v4z * THIRD;

        float vals[12];
        vals[0]  = s3 + ms3;
        vals[1]  = s4 + ms4;
        vals[2]  = s5 + ms5;
        vals[3]  = v3x + bAx + bBx;
        vals[4]  = v3y + bAy + bBy;
        vals[5]  = v3z + crz + mzc;
        vals[6]  = v4x + wsp1 * s1l * uspx;
        vals[7]  = v4y + wsp1 * s1l * uspy;
        vals[8]  = v4z;
        vals[9]  = v5x - bAx + bBx;
        vals[10] = v5y - bAy + bBy;
        vals[11] = v5z - crz + mzc;

        __syncthreads();   // overlay free (prev readback done)

        // ---- A writes: word c = (hi,lo); half 100+c = hi; lanes 50..54 zero
        //      the k-tail words 75..79 (halves 150..159) of the SAME rows ----
#pragma unroll
        for (int q = 0; q < 12; ++q) {
            int row = (q < 3) ? (wave * 3 + q) : (16 + wave * 9 + (q - 3));
            if (lane < 50) {
                float x = vals[q];
                _Float16 hi = (_Float16)x;
                _Float16 lo = (_Float16)(x - (float)hi);
                unsigned u = (unsigned)__builtin_bit_cast(unsigned short, hi)
                           | ((unsigned)__builtin_bit_cast(unsigned short, lo) << 16);
                A32[row * 84 + lane] = u;
                A[row * 168 + 100 + lane] = hi;
            } else if (lane < 55) {
                A32[row * 84 + 25 + lane] = 0u;   // words 75..79
            }
        }
        __syncthreads();   // A complete

        // ---- MFMA phase ----
        f4 acc0, acc1, acc2, acc3, acc4, acc5;
        if (wave < 2) {
            B5 av = ldB5(A + fm * 168 + fq * 8);    // H m-tile (rows 0..15), held
            acc0 = tile5(av, bA);
            acc1 = tile5(av, bB);
            if (wave == 0) {
                bA = ldB5(B1l + 2 * 2560 + fo);
                bB = ldB5(B1l + 3 * 2560 + fo);
                acc2 = tile5(av, bA);
                acc3 = tile5(av, bB);
            } else {
                bA = ldB5(B1l + 6 * 2560 + fo);
                acc2 = tile5(av, bA);
                acc3 = acc0;  // unused
            }
            acc4 = acc0; acc5 = acc0;  // unused
        } else {
            B5 av = ldB5(A + (16 + fm) * 168 + fq * 8);
            acc0 = tile5(av, bA);
            acc1 = tile5(av, bB);
            av = ldB5(A + (32 + fm) * 168 + fq * 8);
            acc2 = tile5(av, bA);
            acc3 = tile5(av, bB);
            av = ldB5(A + (48 + fm) * 168 + fq * 8);
            acc4 = tile5(av, bA);
            acc5 = tile5(av, bB);
        }
        __syncthreads();   // A reads done -> overlay safe

        // ---- C writes, transposed (stride-1 in n) ----
        if (wave < 2) {
            int tb0 = (wave == 0) ? 0 : 4;
#define HWR(TT, ACC) { int n = (TT) * 16 + fm; if (n < 100) { \
            _Pragma("unroll") \
            for (int i = 0; i < 4; ++i) outHT[(fq * 4 + i) * 100 + n] = ACC[i]; } }
            HWR(tb0,     acc0)
            HWR(tb0 + 1, acc1)
            HWR(tb0 + 2, acc2)
            if (wave == 0) HWR(3, acc3)
#undef HWR
        } else {
            int tb0 = (wave == 2) ? 0 : 2;
#define QWR(MQ, TT, ACC) { int n = (TT) * 16 + fm; if (n < 50) { \
            _Pragma("unroll") \
            for (int i = 0; i < 4; ++i) outQT[((MQ) * 16 + fq * 4 + i) * 50 + n] = ACC[i]; } }
            QWR(0, tb0,     acc0)
            QWR(0, tb0 + 1, acc1)
            QWR(1, tb0,     acc2)
            QWR(1, tb0 + 1, acc3)
            QWR(2, tb0,     acc4)
            QWR(2, tb0 + 1, acc5)
#undef QWR
        }
        __syncthreads();   // outputs ready

        // ---- readback + activations ----
        {
            int mb = wave * 3, qb = wave * 9;
            float as3 = outHT[(mb    ) * 100 + kl];
            float as4 = outHT[(mb + 1) * 100 + kl];
            float as5 = outHT[(mb + 2) * 100 + kl];
            float ag3 = outHT[(mb    ) * 100 + 50 + kl];
            float ag4 = outHT[(mb + 1) * 100 + 50 + kl];
            float ag5 = outHT[(mb + 2) * 100 + 50 + kl];
            float g3 = sigm_(ag3), g4 = sigm_(ag4), g5 = sigm_(ag5);
            s3 = silu_(as3); s4 = silu_(as4); s5 = silu_(as5);
            v3x = outQT[(qb    ) * 50 + kl] * g3;
            v3y = outQT[(qb + 1) * 50 + kl] * g3;
            v3z = outQT[(qb + 2) * 50 + kl] * g3;
            v4x = outQT[(qb + 3) * 50 + kl] * g4;
            v4y = outQT[(qb + 4) * 50 + kl] * g4;
            v4z = outQT[(qb + 5) * 50 + kl] * g4;
            v5x = outQT[(qb + 6) * 50 + kl] * g5;
            v5y = outQT[(qb + 7) * 50 + kl] * g5;
            v5z = outQT[(qb + 8) * 50 + kl] * g5;
        }
    }

    // ---- output epilogue ----
    float wo = (lane < 50) ? W_out[lane] : 0.0f;
    float px  = (v3x + v4x + v5x) * wo;
    float py  = (v3y + v4y + v5y) * wo;
    float dxv = (v3x - v5x) * wo;
    float dyv = (v3y - v5y) * wo;
#pragma unroll
    for (int o = 32; o > 0; o >>= 1) {
        px  += __shfl_xor(px, o);
        py  += __shfl_xor(py, o);
        dxv += __shfl_xor(dxv, o);
        dyv += __shfl_xor(dyv, o);
    }
    if (lane == 0) {
        float* op = out + ((size_t)(b * 514 + (tw + 1))) * 3;
        op[0] = px;
        op[1] = py;
        op[2] = offx * dyv - offy * dxv;
    }
}

// ---------------------------------------------------------------------------
extern "C" void kernel_launch(void* const* d_in, const int* in_sizes, int n_in,
                              void* d_out, int out_size, void* d_ws, size_t ws_size,
                              hipStream_t stream) {
    const float* y       = (const float*)d_in[0];
    const float* W_embed = (const float*)d_in[1];
    const float* Wr1     = (const float*)d_in[2];
    const float* br1     = (const float*)d_in[3];
    const float* Wr2     = (const float*)d_in[4];
    const float* Ws      = (const float*)d_in[5];
    const float* Wv      = (const float*)d_in[6];
    const float* Wg      = (const float*)d_in[7];
    const float* W_out   = (const float*)d_in[8];
    float* out = (float*)d_out;

    _Float16* Bws = (_Float16*)d_ws;                         // 337920 B
    float* pre = (float*)((char*)d_ws + B_TOT * 2);          // 1800 floats
    float* T   = pre + 1800;

    int tabN = 2048;
    while (tabN > 64 &&
           (size_t)B_TOT * 2 + (size_t)(1800 + 6 * (tabN + 1) * 100) * sizeof(float) > ws_size)
        tabN >>= 1;

    int nTb = (6 * (tabN + 1) + 3) / 4;
    int nFb = (B_TOT + 255) / 256;
    precompute_all<<<1 + nTb + nFb, 256, 0, stream>>>(
        W_embed, Wr1, br1, Wr2, Ws, Wg, Wv, pre, T, tabN, Bws, out, nTb);
    fused_main<<<8192, 256, 0, stream>>>(y, W_embed, W_out, pre, T, tabN, Bws, out);
}